// Round 1
// baseline (4290.728 us; speedup 1.0000x reference)
//
#include <hip/hip_runtime.h>
#include <hip/hip_bf16.h>

#define M_TOT 16384
#define D_DIM 256
#define C_TOT 8192
#define BMm 128
#define BNn 128
#define BKk 16
#define BSW 144            // 128 + 4-float pad per 32 cols (bank-conflict break)
#define NKT (D_DIM / BKk)  // 16
#define NCH 4              // C split -> grid 512 = 2 blocks/CU
#define CCH (C_TOT / NCH)  // 2048
#define NCT (CCH / BNn)    // 16
#define QOFF (M_TOT * D_DIM)

// swizzle: physical column with +4 floats pad every 32 (keeps 16B alignment)
__device__ __forceinline__ int pcol(int c) { return c + ((c >> 5) << 2); }

// ---------------- kernel 0: row sums of squares (x2, e2) ----------------
__global__ void sq_kernel(const float* __restrict__ x, const float* __restrict__ e,
                          float* __restrict__ x2, float* __restrict__ e2) {
    int row  = blockIdx.x * 4 + (threadIdx.x >> 6);
    int lane = threadIdx.x & 63;
    const float* src = (row < M_TOT) ? (x + (size_t)row * D_DIM)
                                     : (e + (size_t)(row - M_TOT) * D_DIM);
    float4 v = *(const float4*)(src + lane * 4);
    float s = v.x * v.x + v.y * v.y + v.z * v.z + v.w * v.w;
    #pragma unroll
    for (int off = 32; off >= 1; off >>= 1) s += __shfl_xor(s, off, 64);
    if (lane == 0) { if (row < M_TOT) x2[row] = s; else e2[row - M_TOT] = s; }
}

// ------------- kernel 1: tiled fp32 GEMM + fused running argmin -------------
__global__ __launch_bounds__(256, 2) void dist_kernel(
    const float* __restrict__ x, const float* __restrict__ e,
    const float* __restrict__ x2, const float* __restrict__ e2,
    float* __restrict__ bestv, int* __restrict__ besti)
{
    __shared__ __align__(16) float As[2][BKk][BMm];
    __shared__ __align__(16) float Bs[2][BKk][BSW];

    const int t  = threadIdx.x;
    const int ty = t >> 4, tx = t & 15;
    const int mt = (int)blockIdx.x >> 2;
    const int ch = (int)blockIdx.x & 3;
    const int m0 = mt * BMm;
    const int c0 = ch * CCH;

    float x2r[8];
    #pragma unroll
    for (int i = 0; i < 8; ++i) x2r[i] = x2[m0 + ty * 8 + i];

    float best[8]; int bidx[8];
    #pragma unroll
    for (int i = 0; i < 8; ++i) { best[i] = 3.4e38f; bidx[i] = 0; }

    const int r0  = t >> 2;        // row-in-tile (it adds +64)
    const int cq0 = (t & 3) << 2;  // k sub-column 0/4/8/12

    for (int ct = 0; ct < NCT; ++ct) {
        const int cb = c0 + ct * BNn;
        float acc[8][8];
        #pragma unroll
        for (int i = 0; i < 8; ++i)
            #pragma unroll
            for (int j = 0; j < 8; ++j) acc[i][j] = 0.f;

        // stage k-tile 0 into buffer 0 (transposed into k-major)
        #pragma unroll
        for (int it = 0; it < 2; ++it) {
            int r = r0 + it * 64;
            float4 va = *(const float4*)(x + (size_t)(m0 + r) * D_DIM + cq0);
            float4 vb = *(const float4*)(e + (size_t)(cb + r) * D_DIM + cq0);
            As[0][cq0 + 0][r] = va.x; As[0][cq0 + 1][r] = va.y;
            As[0][cq0 + 2][r] = va.z; As[0][cq0 + 3][r] = va.w;
            int pr = pcol(r);
            Bs[0][cq0 + 0][pr] = vb.x; Bs[0][cq0 + 1][pr] = vb.y;
            Bs[0][cq0 + 2][pr] = vb.z; Bs[0][cq0 + 3][pr] = vb.w;
        }
        __syncthreads();

        #pragma unroll 1
        for (int kt = 0; kt < NKT; ++kt) {
            const int cur = kt & 1;
            float4 pa[2], pb[2];
            if (kt + 1 < NKT) {   // prefetch next k-tile into registers
                const int k0 = (kt + 1) * BKk;
                #pragma unroll
                for (int it = 0; it < 2; ++it) {
                    int r = r0 + it * 64;
                    pa[it] = *(const float4*)(x + (size_t)(m0 + r) * D_DIM + k0 + cq0);
                    pb[it] = *(const float4*)(e + (size_t)(cb + r) * D_DIM + k0 + cq0);
                }
            }
            // compute on buffer `cur`
            #pragma unroll
            for (int k = 0; k < BKk; ++k) {
                float a[8], b[8];
                *(float4*)&a[0] = *(const float4*)&As[cur][k][ty * 8];
                *(float4*)&a[4] = *(const float4*)&As[cur][k][ty * 8 + 4];
                const int pb0 = pcol(tx * 8);
                *(float4*)&b[0] = *(const float4*)&Bs[cur][k][pb0];
                *(float4*)&b[4] = *(const float4*)&Bs[cur][k][pb0 + 4];
                #pragma unroll
                for (int i = 0; i < 8; ++i)
                    #pragma unroll
                    for (int j = 0; j < 8; ++j)
                        acc[i][j] = fmaf(a[i], b[j], acc[i][j]);
            }
            __syncthreads();
            if (kt + 1 < NKT) {   // write prefetched tile to other buffer
                const int nb = cur ^ 1;
                #pragma unroll
                for (int it = 0; it < 2; ++it) {
                    int r = r0 + it * 64;
                    As[nb][cq0 + 0][r] = pa[it].x; As[nb][cq0 + 1][r] = pa[it].y;
                    As[nb][cq0 + 2][r] = pa[it].z; As[nb][cq0 + 3][r] = pa[it].w;
                    int pr = pcol(r);
                    Bs[nb][cq0 + 0][pr] = pb[it].x; Bs[nb][cq0 + 1][pr] = pb[it].y;
                    Bs[nb][cq0 + 2][pr] = pb[it].z; Bs[nb][cq0 + 3][pr] = pb[it].w;
                }
                __syncthreads();
            }
        }

        // epilogue: d2 = (x2 - 2*dot) + e2, running argmin (ascending c => '<' keeps first)
        float e2v[8];
        #pragma unroll
        for (int j = 0; j < 8; ++j) e2v[j] = e2[cb + tx * 8 + j];
        #pragma unroll
        for (int i = 0; i < 8; ++i) {
            #pragma unroll
            for (int j = 0; j < 8; ++j) {
                float d = (x2r[i] - 2.0f * acc[i][j]) + e2v[j];
                int c = cb + tx * 8 + j;
                if (d < best[i]) { best[i] = d; bidx[i] = c; }
            }
        }
    }

    // merge across the 16 lanes (same ty) sharing each row; ties -> lower index
    #pragma unroll
    for (int i = 0; i < 8; ++i) {
        float v = best[i]; int idx = bidx[i];
        #pragma unroll
        for (int off = 8; off >= 1; off >>= 1) {
            float ov = __shfl_xor(v, off, 64);
            int   oi = __shfl_xor(idx, off, 64);
            if (ov < v || (ov == v && oi < idx)) { v = ov; idx = oi; }
        }
        if (tx == 0) {
            int row = m0 + ty * 8 + i;
            bestv[ch * M_TOT + row] = v;
            besti[ch * M_TOT + row] = idx;
        }
    }
}

// ------------- kernel 2: merge C-chunks, write indices, gather rows -------------
__global__ void finalize_kernel(const float* __restrict__ e,
                                const float* __restrict__ bestv,
                                const int* __restrict__ besti,
                                float* __restrict__ out)
{
    int m    = blockIdx.x * 4 + (threadIdx.x >> 6);
    int lane = threadIdx.x & 63;
    float bv = bestv[m]; int bi = besti[m];
    #pragma unroll
    for (int h = 1; h < NCH; ++h) {   // chunks ordered by c-range: '<' keeps lowest index on tie
        float v = bestv[h * M_TOT + m];
        if (v < bv) { bv = v; bi = besti[h * M_TOT + m]; }
    }
    if (lane == 0) out[QOFF + m] = (float)bi;
    float4 v = *(const float4*)(e + (size_t)bi * D_DIM + lane * 4);
    *(float4*)(out + (size_t)m * D_DIM + lane * 4) = v;
}

extern "C" void kernel_launch(void* const* d_in, const int* in_sizes, int n_in,
                              void* d_out, int out_size, void* d_ws, size_t ws_size,
                              hipStream_t stream) {
    const float* x = (const float*)d_in[0];   // [16384, 256]
    const float* e = (const float*)d_in[1];   // [8192, 256]
    float* out = (float*)d_out;

    float* wsf   = (float*)d_ws;
    float* x2    = wsf;                                   // 16384
    float* e2    = wsf + M_TOT;                           // 8192
    float* bestv = wsf + M_TOT + C_TOT;                   // 4 * 16384
    int*   besti = (int*)(wsf + M_TOT + C_TOT + NCH * M_TOT); // 4 * 16384

    sq_kernel<<<(M_TOT + C_TOT) / 4, 256, 0, stream>>>(x, e, x2, e2);
    dist_kernel<<<(M_TOT / BMm) * NCH, 256, 0, stream>>>(x, e, x2, e2, bestv, besti);
    finalize_kernel<<<M_TOT / 4, 256, 0, stream>>>(e, bestv, besti, out);
}

// Round 3
// 324.053 us; speedup vs baseline: 13.2408x; 13.2408x over previous
//
#include <hip/hip_runtime.h>
#include <hip/hip_bf16.h>

#define M_TOT 16384
#define D_DIM 256
#define C_TOT 8192
#define NCH 4
#define CCH (C_TOT / NCH)     // 2048
#define QOFF (M_TOT * D_DIM)
#define NPART 8

typedef _Float16 f16;
typedef __attribute__((ext_vector_type(8))) _Float16 f16x8;
typedef __attribute__((ext_vector_type(4))) float f32x4;

// ---- workspace layout (float units) ----
#define WS_X2 0
#define WS_E2 (M_TOT)
#define WS_BV (M_TOT + C_TOT)
#define WS_BI (WS_BV + NPART * M_TOT)
#define WS_SPL (WS_BI + NPART * M_TOT)
// half-unit offsets within the split region
#define XH_OFF ((size_t)0)
#define XL_OFF ((size_t)M_TOT * D_DIM)
#define EH_OFF ((size_t)2 * M_TOT * D_DIM)
#define EL_OFF ((size_t)2 * M_TOT * D_DIM + (size_t)C_TOT * D_DIM)
#define SPL_HALFS ((size_t)2 * M_TOT * D_DIM + (size_t)2 * C_TOT * D_DIM)
#define WS_NEED ((size_t)WS_SPL * 4 + SPL_HALFS * 2)

__device__ __forceinline__ void gll16(const void* g, void* l) {
    __builtin_amdgcn_global_load_lds((const __attribute__((address_space(1))) void*)g,
                                     (__attribute__((address_space(3))) void*)l, 16, 0, 0);
}

// ---------- split: fp16 (hi,lo) decomposition + row sums of squares ----------
// x scaled by 2^8, e scaled by 2^14 (keeps lo-parts out of fp16 subnormal danger;
// exact power-of-2 scales, undone by 2^-21 on 2*xe).
__global__ void split_kernel(const float* __restrict__ x, const float* __restrict__ e,
                             f16* __restrict__ sp, float* __restrict__ x2, float* __restrict__ e2)
{
    int row  = blockIdx.x * 4 + (threadIdx.x >> 6);
    int lane = threadIdx.x & 63;
    bool isx = row < M_TOT;
    int r = isx ? row : row - M_TOT;
    const float* src = (isx ? x : e) + (size_t)r * D_DIM;
    float4 v = *(const float4*)(src + lane * 4);
    float s = v.x * v.x + v.y * v.y + v.z * v.z + v.w * v.w;  // ORIGINAL scale (matches ref x2/e2)
    #pragma unroll
    for (int off = 32; off >= 1; off >>= 1) s += __shfl_xor(s, off, 64);
    float sc = isx ? 256.0f : 16384.0f;
    float a[4] = {v.x * sc, v.y * sc, v.z * sc, v.w * sc};
    union { f16 h[4]; ushort4 u; } hh, ll;
    #pragma unroll
    for (int i = 0; i < 4; ++i) {
        f16 h = (f16)a[i];
        hh.h[i] = h;
        ll.h[i] = (f16)(a[i] - (float)h);
    }
    size_t base = (size_t)r * D_DIM + lane * 4;
    f16* ph = sp + (isx ? XH_OFF : EH_OFF) + base;
    f16* pl = sp + (isx ? XL_OFF : EL_OFF) + base;
    *(ushort4*)ph = hh.u;
    *(ushort4*)pl = ll.u;
    if (lane == 0) { if (isx) x2[r] = s; else e2[r] = s; }
}

// ---------- MFMA distance + fused argmin ----------
// 128x128 tile, 4 waves (2x2, 64x64 each), BK=32, K=256 (8 k-steps),
// S = xh*eh + xh*el + xl*eh accumulated fp32; d = fma(S, -2^-21, x2) + e2.
// LDS fragment-major: tensor tn in {Ah,Al,Bh,Bl}, halfs offset tn*4096 + (kb*128+row)*8.
__global__ __launch_bounds__(256, 2) void mdist_kernel(
    const f16* __restrict__ sp, const float* __restrict__ x2, const float* __restrict__ e2,
    float* __restrict__ bestv, int* __restrict__ besti)
{
    __shared__ __align__(16) f16 lds[2][16384];  // 2 x 32 KB

    const int t  = threadIdx.x;
    const int l  = t & 63;
    const int wv = t >> 6;
    const int wr = wv >> 1, wc = wv & 1;
    const int mt = (int)blockIdx.x >> 2;
    const int ch = (int)blockIdx.x & 3;
    const int m0 = mt * 128, c0 = ch * CCH;

    // staging decomposition: slot s = it*256+t -> tn=it>>1, kb=((it&1)<<1)+(t>>7), row=t&127
    const int sr = t & 127;
    const f16* aA[4];
    #pragma unroll
    for (int it = 0; it < 4; ++it) {
        int kb = ((it & 1) << 1) + (t >> 7);
        const f16* tp = sp + ((it >> 1) == 0 ? XH_OFF : XL_OFF);
        aA[it] = tp + (size_t)(m0 + sr) * D_DIM + kb * 8;
    }

    const int kbf = l >> 4;   // fragment k-block
    const int fr  = l & 15;   // fragment row/col lane

    auto bptr = [&](int it, int ctv) -> const f16* {
        int kb = ((it & 1) << 1) + (t >> 7);
        const f16* tp = sp + ((it >> 1) == 0 ? EH_OFF : EL_OFF);
        return tp + (size_t)(c0 + ctv * 128 + sr) * D_DIM + kb * 8;
    };
    auto STAGE = [&](int buf, int ktv, int ctv) {
        char* base = (char*)&lds[buf][0];
        #pragma unroll
        for (int it = 0; it < 4; ++it)
            gll16(aA[it] + ktv * 32, base + (it * 256 + t) * 16);
        #pragma unroll
        for (int it = 0; it < 4; ++it)
            gll16(bptr(it, ctv) + ktv * 32, base + ((it + 4) * 256 + t) * 16);
    };

    float bst[16]; int bix[16];
    #pragma unroll
    for (int i = 0; i < 16; ++i) { bst[i] = 3.4e38f; bix[i] = 0; }

    STAGE(0, 0, 0);

    for (int ct = 0; ct < 16; ++ct) {
        const int cb = c0 + ct * 128;
        f32x4 acc[4][4];
        #pragma unroll
        for (int m = 0; m < 4; ++m)
            #pragma unroll
            for (int n = 0; n < 4; ++n)
                #pragma unroll
                for (int k = 0; k < 4; ++k) acc[m][n][k] = 0.f;

        #pragma unroll 1
        for (int kt = 0; kt < 8; ++kt) {
            const int cur = kt & 1;
            // EXPLICIT drain of the LDS-DMA loads that staged lds[cur] (issued
            // last iteration). Do not rely on __syncthreads()'s fence covering
            // vmcnt for global_load_lds — race seen on replay without this.
            asm volatile("s_waitcnt vmcnt(0)" ::: "memory");
            __syncthreads();
            __builtin_amdgcn_sched_barrier(0);  // pin: no reads hoisted above barrier

            if (kt < 7)            STAGE(cur ^ 1, kt + 1, ct);
            else if (ct < 15)      STAGE(cur ^ 1, 0, ct + 1);

            const f16* L = &lds[cur][0];
            f16x8 bh[4], bl[4];
            #pragma unroll
            for (int n = 0; n < 4; ++n) {
                int boff = (kbf * 128 + wc * 64 + n * 16 + fr) * 8;
                bh[n] = *(const f16x8*)(L + 2 * 4096 + boff);
                bl[n] = *(const f16x8*)(L + 3 * 4096 + boff);
            }
            #pragma unroll
            for (int m = 0; m < 4; ++m) {
                int aoff = (kbf * 128 + wr * 64 + m * 16 + fr) * 8;
                f16x8 ah = *(const f16x8*)(L + aoff);
                f16x8 al = *(const f16x8*)(L + 4096 + aoff);
                #pragma unroll
                for (int n = 0; n < 4; ++n) {
                    acc[m][n] = __builtin_amdgcn_mfma_f32_16x16x32_f16(ah, bh[n], acc[m][n], 0, 0, 0);
                    acc[m][n] = __builtin_amdgcn_mfma_f32_16x16x32_f16(ah, bl[n], acc[m][n], 0, 0, 0);
                    acc[m][n] = __builtin_amdgcn_mfma_f32_16x16x32_f16(al, bh[n], acc[m][n], 0, 0, 0);
                }
            }
        }

        // epilogue: fold into running argmin. cols ascend with ct => strict '<' keeps first.
        float e2v[4];
        #pragma unroll
        for (int n = 0; n < 4; ++n) e2v[n] = e2[cb + wc * 64 + n * 16 + fr];
        #pragma unroll
        for (int m = 0; m < 4; ++m) {
            #pragma unroll
            for (int j = 0; j < 4; ++j) {
                float xv = x2[m0 + wr * 64 + m * 16 + (l >> 4) * 4 + j];
                int bi = m * 4 + j;
                #pragma unroll
                for (int n = 0; n < 4; ++n) {
                    float d = fmaf(acc[m][n][j], -0x1p-21f, xv) + e2v[n];
                    int c = cb + wc * 64 + n * 16 + fr;
                    if (d < bst[bi]) { bst[bi] = d; bix[bi] = c; }
                }
            }
        }
    }

    // merge the 16 lanes sharing each output row (lanes q*16 .. q*16+15); ties -> lower col
    #pragma unroll
    for (int i = 0; i < 16; ++i) {
        float v = bst[i]; int idx = bix[i];
        #pragma unroll
        for (int off = 8; off >= 1; off >>= 1) {
            float ov = __shfl_xor(v, off, 64);
            int   oi = __shfl_xor(idx, off, 64);
            if (ov < v || (ov == v && oi < idx)) { v = ov; idx = oi; }
        }
        if (fr == 0) {
            int row = m0 + wr * 64 + (i >> 2) * 16 + (l >> 4) * 4 + (i & 3);
            int p = ch * 2 + wc;
            bestv[p * M_TOT + row] = v;
            besti[p * M_TOT + row] = idx;
        }
    }
}

// ---------- finalize: merge partials (explicit index tie-break), gather ----------
__global__ void finalize_kernel(const float* __restrict__ e,
                                const float* __restrict__ bestv,
                                const int* __restrict__ besti,
                                float* __restrict__ out, int npart)
{
    int m    = blockIdx.x * 4 + (threadIdx.x >> 6);
    int lane = threadIdx.x & 63;
    float bv = bestv[m]; int bi = besti[m];
    for (int h = 1; h < npart; ++h) {
        float v = bestv[h * M_TOT + m];
        int   i2 = besti[h * M_TOT + m];
        if (v < bv || (v == bv && i2 < bi)) { bv = v; bi = i2; }
    }
    if (lane == 0) out[QOFF + m] = (float)bi;
    float4 v = *(const float4*)(e + (size_t)bi * D_DIM + lane * 4);
    *(float4*)(out + (size_t)m * D_DIM + lane * 4) = v;
}

// ================= fallback fp32 path (only if ws too small) =================
#define BMm 128
#define BNn 128
#define BKk 16
#define BSW 144
#define NKT (D_DIM / BKk)
#define NCT (CCH / BNn)

__device__ __forceinline__ int pcol(int c) { return c + ((c >> 5) << 2); }

__global__ void sq_kernel(const float* __restrict__ x, const float* __restrict__ e,
                          float* __restrict__ x2, float* __restrict__ e2) {
    int row  = blockIdx.x * 4 + (threadIdx.x >> 6);
    int lane = threadIdx.x & 63;
    const float* src = (row < M_TOT) ? (x + (size_t)row * D_DIM)
                                     : (e + (size_t)(row - M_TOT) * D_DIM);
    float4 v = *(const float4*)(src + lane * 4);
    float s = v.x * v.x + v.y * v.y + v.z * v.z + v.w * v.w;
    #pragma unroll
    for (int off = 32; off >= 1; off >>= 1) s += __shfl_xor(s, off, 64);
    if (lane == 0) { if (row < M_TOT) x2[row] = s; else e2[row - M_TOT] = s; }
}

__global__ __launch_bounds__(256, 1) void dist_kernel(
    const float* __restrict__ x, const float* __restrict__ e,
    const float* __restrict__ x2, const float* __restrict__ e2,
    float* __restrict__ bestv, int* __restrict__ besti)
{
    __shared__ __align__(16) float As[2][BKk][BMm];
    __shared__ __align__(16) float Bs[2][BKk][BSW];
    const int t  = threadIdx.x;
    const int ty = t >> 4, tx = t & 15;
    const int mt = (int)blockIdx.x >> 2;
    const int ch = (int)blockIdx.x & 3;
    const int m0 = mt * BMm, c0 = ch * CCH;
    float x2r[8];
    #pragma unroll
    for (int i = 0; i < 8; ++i) x2r[i] = x2[m0 + ty * 8 + i];
    float best[8]; int bidx[8];
    #pragma unroll
    for (int i = 0; i < 8; ++i) { best[i] = 3.4e38f; bidx[i] = 0; }
    const int r0  = t >> 2;
    const int cq0 = (t & 3) << 2;
    for (int ct = 0; ct < NCT; ++ct) {
        const int cb = c0 + ct * BNn;
        float acc[8][8];
        #pragma unroll
        for (int i = 0; i < 8; ++i)
            #pragma unroll
            for (int j = 0; j < 8; ++j) acc[i][j] = 0.f;
        #pragma unroll
        for (int it = 0; it < 2; ++it) {
            int r = r0 + it * 64;
            float4 va = *(const float4*)(x + (size_t)(m0 + r) * D_DIM + cq0);
            float4 vb = *(const float4*)(e + (size_t)(cb + r) * D_DIM + cq0);
            As[0][cq0 + 0][r] = va.x; As[0][cq0 + 1][r] = va.y;
            As[0][cq0 + 2][r] = va.z; As[0][cq0 + 3][r] = va.w;
            int pr = pcol(r);
            Bs[0][cq0 + 0][pr] = vb.x; Bs[0][cq0 + 1][pr] = vb.y;
            Bs[0][cq0 + 2][pr] = vb.z; Bs[0][cq0 + 3][pr] = vb.w;
        }
        __syncthreads();
        #pragma unroll 1
        for (int kt = 0; kt < NKT; ++kt) {
            const int cur = kt & 1;
            float4 pa[2], pb[2];
            if (kt + 1 < NKT) {
                const int k0 = (kt + 1) * BKk;
                #pragma unroll
                for (int it = 0; it < 2; ++it) {
                    int r = r0 + it * 64;
                    pa[it] = *(const float4*)(x + (size_t)(m0 + r) * D_DIM + k0 + cq0);
                    pb[it] = *(const float4*)(e + (size_t)(cb + r) * D_DIM + k0 + cq0);
                }
            }
            #pragma unroll
            for (int k = 0; k < BKk; ++k) {
                float a[8], b[8];
                *(float4*)&a[0] = *(const float4*)&As[cur][k][ty * 8];
                *(float4*)&a[4] = *(const float4*)&As[cur][k][ty * 8 + 4];
                const int pb0 = pcol(tx * 8);
                *(float4*)&b[0] = *(const float4*)&Bs[cur][k][pb0];
                *(float4*)&b[4] = *(const float4*)&Bs[cur][k][pb0 + 4];
                #pragma unroll
                for (int i = 0; i < 8; ++i)
                    #pragma unroll
                    for (int j = 0; j < 8; ++j)
                        acc[i][j] = fmaf(a[i], b[j], acc[i][j]);
            }
            __syncthreads();
            if (kt + 1 < NKT) {
                const int nb = cur ^ 1;
                #pragma unroll
                for (int it = 0; it < 2; ++it) {
                    int r = r0 + it * 64;
                    As[nb][cq0 + 0][r] = pa[it].x; As[nb][cq0 + 1][r] = pa[it].y;
                    As[nb][cq0 + 2][r] = pa[it].z; As[nb][cq0 + 3][r] = pa[it].w;
                    int pr = pcol(r);
                    Bs[nb][cq0 + 0][pr] = pb[it].x; Bs[nb][cq0 + 1][pr] = pb[it].y;
                    Bs[nb][cq0 + 2][pr] = pb[it].z; Bs[nb][cq0 + 3][pr] = pb[it].w;
                }
                __syncthreads();
            }
        }
        float e2v[8];
        #pragma unroll
        for (int j = 0; j < 8; ++j) e2v[j] = e2[cb + tx * 8 + j];
        #pragma unroll
        for (int i = 0; i < 8; ++i) {
            #pragma unroll
            for (int j = 0; j < 8; ++j) {
                float d = (x2r[i] - 2.0f * acc[i][j]) + e2v[j];
                int c = cb + tx * 8 + j;
                if (d < best[i]) { best[i] = d; bidx[i] = c; }
            }
        }
    }
    #pragma unroll
    for (int i = 0; i < 8; ++i) {
        float v = best[i]; int idx = bidx[i];
        #pragma unroll
        for (int off = 8; off >= 1; off >>= 1) {
            float ov = __shfl_xor(v, off, 64);
            int   oi = __shfl_xor(idx, off, 64);
            if (ov < v || (ov == v && oi < idx)) { v = ov; idx = oi; }
        }
        if (tx == 0) {
            int row = m0 + ty * 8 + i;
            bestv[ch * M_TOT + row] = v;
            besti[ch * M_TOT + row] = idx;
        }
    }
}

extern "C" void kernel_launch(void* const* d_in, const int* in_sizes, int n_in,
                              void* d_out, int out_size, void* d_ws, size_t ws_size,
                              hipStream_t stream) {
    const float* x = (const float*)d_in[0];   // [16384, 256]
    const float* e = (const float*)d_in[1];   // [8192, 256]
    float* out = (float*)d_out;

    float* wsf   = (float*)d_ws;
    float* x2    = wsf + WS_X2;
    float* e2    = wsf + WS_E2;
    float* bestv = wsf + WS_BV;
    int*   besti = (int*)(wsf + WS_BI);

    if (ws_size >= WS_NEED) {
        f16* sp = (f16*)(wsf + WS_SPL);
        split_kernel<<<(M_TOT + C_TOT) / 4, 256, 0, stream>>>(x, e, sp, x2, e2);
        mdist_kernel<<<(M_TOT / 128) * NCH, 256, 0, stream>>>(sp, x2, e2, bestv, besti);
        finalize_kernel<<<M_TOT / 4, 256, 0, stream>>>(e, bestv, besti, out, NPART);
    } else {
        sq_kernel<<<(M_TOT + C_TOT) / 4, 256, 0, stream>>>(x, e, x2, e2);
        dist_kernel<<<(M_TOT / BMm) * NCH, 256, 0, stream>>>(x, e, x2, e2, bestv, besti);
        finalize_kernel<<<M_TOT / 4, 256, 0, stream>>>(e, bestv, besti, out, NCH);
    }
}